// Round 10
// baseline (112.473 us; speedup 1.0000x reference)
//
#include <hip/hip_runtime.h>
#include <hip/hip_bf16.h>
#include <math.h>

// NT-Xent loss, N=4096, D=256 -> 2N=8192 rows.
// R10: R9's row-major partial caused 800K scattered 4B stores -> 88MB of HBM
// write-allocate RMW (WRITE 54.8MB/FETCH 31.7MB). Revert to SLOT-MAJOR
// partial[128][8192] (epilogue stores contiguous, ~10MB), and add a dedicated
// coalesced transpose-reduce kernel (K3) so the loss kernel reads scalar
// rowsums. Also drop simsum's launch_bounds VGPR clamp (R9: 64 VGPR limited
// outstanding loads). NOTE: dur_us includes the harness's fixed ~43us poison
// fill of the 268MB d_ws -> our controllable budget is dur-43.
// K1 prep: normalize -> fp8, chunk-transposed zT[k8][row] (32 x 8192 x 8B).
// K2 simsum: LDS-free fp8 MFMA Gram over upper-tri 128x128 tiles; privatized
//    no-atomic epilogue -> partial[slot][row], unique writer per slot.
// K3 reduce: partial -> rowsum (fully coalesced). K4 loss. K5 final.

static constexpr int ROWS  = 8192;
static constexpr int NPAIR = 4096;
static constexpr int DIM   = 256;            // bytes per fp8 row
static constexpr int NTILE = 64 * 65 / 2;    // 2080
static constexpr float EXP_SCALE = 14.426950408889634f;  // 10/ln2
static constexpr size_t CH = 65536;          // bytes per zT chunk-row: 8192*8

typedef float f32x4 __attribute__((ext_vector_type(4)));

template <int CTRL>
__device__ __forceinline__ float dpp_add(float x) {
    int t = __builtin_amdgcn_update_dpp(
        0, __builtin_bit_cast(int, x), CTRL, 0xF, 0xF, true);
    return x + __builtin_bit_cast(float, t);
}
// butterfly sum over each 16-lane group (full-rate VALU DPP)
__device__ __forceinline__ float sum16(float x) {
    x = dpp_add<0xB1>(x);   // xor 1
    x = dpp_add<0x4E>(x);   // xor 2
    x = dpp_add<0x141>(x);  // xor 4 (row_half_mirror)
    x = dpp_add<0x140>(x);  // xor 8 (row_mirror)
    return x;
}
__device__ __forceinline__ float sum64(float x) {
    x = sum16(x);
    x += __shfl_xor(x, 16);
    x += __shfl_xor(x, 32);
    return x;
}

// ---------------- K1: normalize -> fp8 -> chunk-transposed zT ----------------
__global__ void __launch_bounds__(256) prep_kernel(
        const float* __restrict__ z1, const float* __restrict__ z2,
        unsigned char* __restrict__ zT, float* __restrict__ invnorm) {
    __shared__ int Ls[16 * 64];   // 16 rows x 256B
    const int tid  = threadIdx.x;
    const int wave = tid >> 6;
    const int lane = tid & 63;
    const int r0   = blockIdx.x * 16;

    #pragma unroll
    for (int it = 0; it < 4; ++it) {
        const int row = r0 + it * 4 + wave;
        const float* src = (row < NPAIR) ? (z1 + (size_t)row * DIM)
                                         : (z2 + (size_t)(row - NPAIR) * DIM);
        float4 v = ((const float4*)src)[lane];
        float ss = sum64(v.x * v.x + v.y * v.y + v.z * v.z + v.w * v.w);
        float invn = 1.0f / fmaxf(sqrtf(ss), 1e-12f);
        int p = __builtin_amdgcn_cvt_pk_fp8_f32(v.x * invn, v.y * invn, 0, false);
        p     = __builtin_amdgcn_cvt_pk_fp8_f32(v.z * invn, v.w * invn, p, true);
        Ls[(it * 4 + wave) * 64 + lane] = p;
        if (lane == 0) invnorm[row] = invn;
    }
    __syncthreads();
    // transpose out: thread t -> chunk k8 = t>>3, row pair rp = t&7
    const int k8 = tid >> 3;
    const int rp = (tid & 7) * 2;
    int4 o;
    o.x = Ls[rp * 64 + k8 * 2];
    o.y = Ls[rp * 64 + k8 * 2 + 1];
    o.z = Ls[(rp + 1) * 64 + k8 * 2];
    o.w = Ls[(rp + 1) * 64 + k8 * 2 + 1];
    *(int4*)(zT + (size_t)k8 * CH + (size_t)(r0 + rp) * 8) = o;
}

// ---------------- K2: symmetric fp8 Gram, LDS-free ----------------
__global__ void simsum_kernel(
        const unsigned char* __restrict__ zT, float* __restrict__ partial) {
    // decode linear tile index -> (by, bx), bx >= by
    const int t = blockIdx.x;
    int by = (int)floorf((129.0f - sqrtf(16641.0f - 8.0f * (float)t)) * 0.5f);
    by = max(0, min(by, 63));
    while (64 * (by + 1) - ((by + 1) * by) / 2 <= t) by++;
    while (64 * by - (by * (by - 1)) / 2 > t) by--;
    const int bx = by + (t - (64 * by - (by * (by - 1)) / 2));
    const int rowBase = by * 128;
    const int colBase = bx * 128;

    const int tid  = threadIdx.x;
    const int wave = tid >> 6;
    const int lane = tid & 63;
    const int lc   = lane & 15;
    const int quad = lane >> 4;
    const int waveRow = (wave >> 1) * 64;
    const int waveCol = (wave & 1) * 64;

    const unsigned char* zA = zT + (size_t)quad * CH
                              + (size_t)(rowBase + waveRow + lc) * 8;
    const unsigned char* zB = zT + (size_t)quad * CH
                              + (size_t)(colBase + waveCol + lc) * 8;

    f32x4 acc[4][4];
    #pragma unroll
    for (int i = 0; i < 4; i++)
        #pragma unroll
        for (int j = 0; j < 4; j++)
            acc[i][j] = (f32x4)(0.0f);

    #pragma unroll
    for (int ks = 0; ks < 8; ks++) {
        long af[4], bfr[4];
        #pragma unroll
        for (int i = 0; i < 4; i++)
            af[i] = *(const long*)(zA + (size_t)ks * 4 * CH + i * 128);
        #pragma unroll
        for (int j = 0; j < 4; j++)
            bfr[j] = *(const long*)(zB + (size_t)ks * 4 * CH + j * 128);
        #pragma unroll
        for (int i = 0; i < 4; i++)
            #pragma unroll
            for (int j = 0; j < 4; j++)
                acc[i][j] = __builtin_amdgcn_mfma_f32_16x16x32_fp8_fp8(
                    af[i], bfr[j], acc[i][j], 0, 0, 0);
    }

    // Epilogue. C/D 16x16: col=lane&15, row=quad*4+reg [m89].
    // Privatized unique-writer slots, SLOT-MAJOR: partial[slot*8192 + row]
    // (stores from the 4 quads land 16B apart -> contiguous lines).
    float* prow = partial + (size_t)(bx * 2 + (waveCol >> 6)) * ROWS;
    if (bx == by) {
        #pragma unroll
        for (int i = 0; i < 4; i++) {
            #pragma unroll
            for (int r = 0; r < 4; r++) {
                const int grow = rowBase + waveRow + 16 * i + quad * 4 + r;
                float s = 0.0f;
                #pragma unroll
                for (int j = 0; j < 4; j++) {
                    const int gcol = colBase + waveCol + 16 * j + lc;
                    float e = __builtin_amdgcn_exp2f(acc[i][j][r] * EXP_SCALE);
                    s += (grow == gcol) ? 0.0f : e;
                }
                s = sum16(s);
                if (lc == 0) prow[grow] = s;
            }
        }
    } else {
        float* pcol = partial + (size_t)(by * 2 + (waveRow >> 6)) * ROWS;
        float colacc[4] = {0.0f, 0.0f, 0.0f, 0.0f};
        #pragma unroll
        for (int i = 0; i < 4; i++) {
            #pragma unroll
            for (int r = 0; r < 4; r++) {
                const int grow = rowBase + waveRow + 16 * i + quad * 4 + r;
                float s = 0.0f;
                #pragma unroll
                for (int j = 0; j < 4; j++) {
                    float e = __builtin_amdgcn_exp2f(acc[i][j][r] * EXP_SCALE);
                    s += e;
                    colacc[j] += e;
                }
                s = sum16(s);
                if (lc == 0) prow[grow] = s;
            }
        }
        #pragma unroll
        for (int j = 0; j < 4; j++) {
            float c = colacc[j];
            c += __shfl_xor(c, 16);
            c += __shfl_xor(c, 32);
            if (lane < 16) pcol[colBase + waveCol + 16 * j + lc] = c;
        }
    }
}

// ---------------- K3: coalesced transpose-reduce partial -> rowsum ----------
// 128 blocks x 256 thr; block b -> rows b*64..b*64+63; wave w -> slots
// w, w+4, ..., w+124; lane reads partial[s*8192 + r0+lane] (256B coalesced).
__global__ void __launch_bounds__(256) reduce_kernel(
        const float* __restrict__ partial, float* __restrict__ rowsum) {
    const int tid  = threadIdx.x;
    const int wave = tid >> 6;
    const int lane = tid & 63;
    const int r0 = blockIdx.x * 64;
    float s = 0.0f;
    #pragma unroll
    for (int k = 0; k < 32; ++k) {
        const int slot = wave + k * 4;
        s += partial[(size_t)slot * ROWS + r0 + lane];
    }
    __shared__ float red[4][64];
    red[wave][lane] = s;
    __syncthreads();
    if (wave == 0)
        rowsum[r0 + lane] = red[0][lane] + red[1][lane]
                          + red[2][lane] + red[3][lane];
}

// ---------------- K4: per-pair loss -> blockpart (no atomics) ----------------
__global__ void __launch_bounds__(256) loss_kernel(
        const float* __restrict__ z1, const float* __restrict__ z2,
        const float* __restrict__ invnorm, const float* __restrict__ rowsum,
        float* __restrict__ blockpart) {
    const int tid  = threadIdx.x;
    const int wave = tid >> 6;
    const int lane = tid & 63;
    const int p = blockIdx.x * 4 + wave;     // pair 0..4095; rows p, p+NPAIR
    float4 a = ((const float4*)(z1 + (size_t)p * DIM))[lane];
    float4 b = ((const float4*)(z2 + (size_t)p * DIM))[lane];
    float d = sum64(a.x * b.x + a.y * b.y + a.z * b.z + a.w * b.w);
    __shared__ float wp[4];
    if (lane == 0) {
        float sim = d * invnorm[p] * invnorm[p + NPAIR] * 10.0f;
        wp[wave] = logf(rowsum[p]) + logf(rowsum[p + NPAIR]) - 2.0f * sim;
    }
    __syncthreads();
    if (tid == 0)
        blockpart[blockIdx.x] = wp[0] + wp[1] + wp[2] + wp[3];
}

// ---------------- K5: final reduce (single block) ----------------
__global__ void __launch_bounds__(256) final_kernel(
        const float* __restrict__ blockpart, float* __restrict__ out) {
    const int tid = threadIdx.x;
    float s = blockpart[tid] + blockpart[tid + 256]
            + blockpart[tid + 512] + blockpart[tid + 768];
    s = sum64(s);
    __shared__ float wpart[4];
    if ((tid & 63) == 0) wpart[tid >> 6] = s;
    __syncthreads();
    if (tid == 0)
        out[0] = (wpart[0] + wpart[1] + wpart[2] + wpart[3]) * (1.0f / ROWS);
}

extern "C" void kernel_launch(void* const* d_in, const int* in_sizes, int n_in,
                              void* d_out, int out_size, void* d_ws, size_t ws_size,
                              hipStream_t stream) {
    const float* z1 = (const float*)d_in[0];
    const float* z2 = (const float*)d_in[1];
    float* out = (float*)d_out;

    char* ws = (char*)d_ws;
    unsigned char* zT = (unsigned char*)ws;                         // 2 MiB
    float* partial   = (float*)(ws + (size_t)2 * 1024 * 1024);      // 4 MiB [slot][row]
    float* invnorm   = (float*)(ws + (size_t)6 * 1024 * 1024);      // 32 KiB
    float* rowsum    = (float*)(ws + (size_t)6 * 1024 * 1024 + 32768);   // 32 KiB
    float* blockpart = (float*)(ws + (size_t)6 * 1024 * 1024 + 65536);   // 4 KiB

    prep_kernel<<<ROWS / 16, 256, 0, stream>>>(z1, z2, zT, invnorm);
    simsum_kernel<<<NTILE, 256, 0, stream>>>(zT, partial);
    reduce_kernel<<<ROWS / 64, 256, 0, stream>>>(partial, rowsum);
    loss_kernel<<<NPAIR / 4, 256, 0, stream>>>(z1, z2, invnorm, rowsum, blockpart);
    final_kernel<<<1, 256, 0, stream>>>(blockpart, out);
}

// Round 11
// 96.417 us; speedup vs baseline: 1.1665x; 1.1665x over previous
//
#include <hip/hip_runtime.h>
#include <hip/hip_bf16.h>
#include <math.h>

// NT-Xent loss, N=4096, D=256 -> 2N=8192 rows.
// R11: simsum is LOAD-LATENCY bound (R10: MfmaUtil 13%, 1.7TB/s, 64 VGPR,
// ~64 x 200cyc L2-hit loads/wave ~= the 13.7Kcyc/block observed; WRITE 49MB
// is poison-flush attribution from the harness's 268MB d_ws fill, not ours).
// Fix: re-pack operand as zT16[c2][row] with 16B per entry (c2 = quad*4+kk
// covers TWO MFMA k-steps) -> 32 global_load_dwordx4 per wave (was 64 x2),
// issued in 4 groups of 8 independent loads, kk-loop unrolled so loads of
// group kk+1 overlap the 32 MFMAs of group kk.
// K1 prep: normalize -> fp8 -> zT16.  K2 simsum: LDS-free fp8 MFMA Gram over
// upper-tri 128x128 tiles, privatized no-atomic slot-major epilogue.
// K3 coalesced reduce -> rowsum.  K4 loss.  K5 final.

static constexpr int ROWS  = 8192;
static constexpr int NPAIR = 4096;
static constexpr int DIM   = 256;            // bytes per fp8 row
static constexpr int NTILE = 64 * 65 / 2;    // 2080
static constexpr float EXP_SCALE = 14.426950408889634f;  // 10/ln2

typedef float f32x4 __attribute__((ext_vector_type(4)));
typedef long  l2v  __attribute__((ext_vector_type(2)));

template <int CTRL>
__device__ __forceinline__ float dpp_add(float x) {
    int t = __builtin_amdgcn_update_dpp(
        0, __builtin_bit_cast(int, x), CTRL, 0xF, 0xF, true);
    return x + __builtin_bit_cast(float, t);
}
__device__ __forceinline__ float sum16(float x) {
    x = dpp_add<0xB1>(x);   // xor 1
    x = dpp_add<0x4E>(x);   // xor 2
    x = dpp_add<0x141>(x);  // xor 4 (row_half_mirror)
    x = dpp_add<0x140>(x);  // xor 8 (row_mirror)
    return x;
}
__device__ __forceinline__ float sum64(float x) {
    x = sum16(x);
    x += __shfl_xor(x, 16);
    x += __shfl_xor(x, 32);
    return x;
}

// ---------------- K1: normalize -> fp8 -> packed zT16 ----------------
// zT16[(c2*8192 + row)*16] : c2 = quad*4 + kk, entry = 16 bytes =
//   z[row][64kk+8q .. +7] ++ z[row][64kk+32+8q .. +7]
__global__ void __launch_bounds__(256) prep_kernel(
        const float* __restrict__ z1, const float* __restrict__ z2,
        unsigned char* __restrict__ zT16, float* __restrict__ invnorm) {
    __shared__ int Ls[16 * 64];   // 16 rows x 256B
    const int tid  = threadIdx.x;
    const int wave = tid >> 6;
    const int lane = tid & 63;
    const int r0   = blockIdx.x * 16;

    #pragma unroll
    for (int it = 0; it < 4; ++it) {
        const int row = r0 + it * 4 + wave;
        const float* src = (row < NPAIR) ? (z1 + (size_t)row * DIM)
                                         : (z2 + (size_t)(row - NPAIR) * DIM);
        float4 v = ((const float4*)src)[lane];
        float ss = sum64(v.x * v.x + v.y * v.y + v.z * v.z + v.w * v.w);
        float invn = 1.0f / fmaxf(sqrtf(ss), 1e-12f);
        int p = __builtin_amdgcn_cvt_pk_fp8_f32(v.x * invn, v.y * invn, 0, false);
        p     = __builtin_amdgcn_cvt_pk_fp8_f32(v.z * invn, v.w * invn, p, true);
        Ls[(it * 4 + wave) * 64 + lane] = p;
        if (lane == 0) invnorm[row] = invn;
    }
    __syncthreads();
    // thread t -> c2 = t>>4, row r = t&15
    const int c2 = tid >> 4;
    const int r  = tid & 15;
    const int quad = c2 >> 2;
    const int kk   = c2 & 3;
    const int d0 = 16 * kk + 2 * quad;
    int4 o;
    o.x = Ls[r * 64 + d0];
    o.y = Ls[r * 64 + d0 + 1];
    o.z = Ls[r * 64 + d0 + 8];
    o.w = Ls[r * 64 + d0 + 9];
    *(int4*)(zT16 + ((size_t)c2 * ROWS + r0 + r) * 16) = o;
}

// ---------------- K2: symmetric fp8 Gram, LDS-free, x4 loads ----------------
__global__ void simsum_kernel(
        const unsigned char* __restrict__ zT16, float* __restrict__ partial) {
    // decode linear tile index -> (by, bx), bx >= by
    const int t = blockIdx.x;
    int by = (int)floorf((129.0f - sqrtf(16641.0f - 8.0f * (float)t)) * 0.5f);
    by = max(0, min(by, 63));
    while (64 * (by + 1) - ((by + 1) * by) / 2 <= t) by++;
    while (64 * by - (by * (by - 1)) / 2 > t) by--;
    const int bx = by + (t - (64 * by - (by * (by - 1)) / 2));
    const int rowBase = by * 128;
    const int colBase = bx * 128;

    const int tid  = threadIdx.x;
    const int wave = tid >> 6;
    const int lane = tid & 63;
    const int lc   = lane & 15;
    const int quad = lane >> 4;
    const int waveRow = (wave >> 1) * 64;
    const int waveCol = (wave & 1) * 64;

    // lane base for its quad's packed chunks
    const unsigned char* zA = zT16
        + ((size_t)(quad * 4) * ROWS + rowBase + waveRow + lc) * 16;
    const unsigned char* zB = zT16
        + ((size_t)(quad * 4) * ROWS + colBase + waveCol + lc) * 16;

    f32x4 acc[4][4];
    #pragma unroll
    for (int i = 0; i < 4; i++)
        #pragma unroll
        for (int j = 0; j < 4; j++)
            acc[i][j] = (f32x4)(0.0f);

    #pragma unroll
    for (int kk = 0; kk < 4; kk++) {
        l2v va[4], vb[4];
        #pragma unroll
        for (int i = 0; i < 4; i++)
            va[i] = *(const l2v*)(zA + ((size_t)kk * ROWS + 16 * i) * 16);
        #pragma unroll
        for (int j = 0; j < 4; j++)
            vb[j] = *(const l2v*)(zB + ((size_t)kk * ROWS + 16 * j) * 16);
        // ks = 2kk (lo halves)
        #pragma unroll
        for (int i = 0; i < 4; i++)
            #pragma unroll
            for (int j = 0; j < 4; j++)
                acc[i][j] = __builtin_amdgcn_mfma_f32_16x16x32_fp8_fp8(
                    va[i].x, vb[j].x, acc[i][j], 0, 0, 0);
        // ks = 2kk+1 (hi halves)
        #pragma unroll
        for (int i = 0; i < 4; i++)
            #pragma unroll
            for (int j = 0; j < 4; j++)
                acc[i][j] = __builtin_amdgcn_mfma_f32_16x16x32_fp8_fp8(
                    va[i].y, vb[j].y, acc[i][j], 0, 0, 0);
    }

    // Epilogue. C/D 16x16: col=lane&15, row=quad*4+reg [m89].
    // Privatized unique-writer slots, SLOT-MAJOR: partial[slot*8192 + row].
    float* prow = partial + (size_t)(bx * 2 + (waveCol >> 6)) * ROWS;
    if (bx == by) {
        #pragma unroll
        for (int i = 0; i < 4; i++) {
            #pragma unroll
            for (int r = 0; r < 4; r++) {
                const int grow = rowBase + waveRow + 16 * i + quad * 4 + r;
                float s = 0.0f;
                #pragma unroll
                for (int j = 0; j < 4; j++) {
                    const int gcol = colBase + waveCol + 16 * j + lc;
                    float e = __builtin_amdgcn_exp2f(acc[i][j][r] * EXP_SCALE);
                    s += (grow == gcol) ? 0.0f : e;
                }
                s = sum16(s);
                if (lc == 0) prow[grow] = s;
            }
        }
    } else {
        float* pcol = partial + (size_t)(by * 2 + (waveRow >> 6)) * ROWS;
        float colacc[4] = {0.0f, 0.0f, 0.0f, 0.0f};
        #pragma unroll
        for (int i = 0; i < 4; i++) {
            #pragma unroll
            for (int r = 0; r < 4; r++) {
                const int grow = rowBase + waveRow + 16 * i + quad * 4 + r;
                float s = 0.0f;
                #pragma unroll
                for (int j = 0; j < 4; j++) {
                    float e = __builtin_amdgcn_exp2f(acc[i][j][r] * EXP_SCALE);
                    s += e;
                    colacc[j] += e;
                }
                s = sum16(s);
                if (lc == 0) prow[grow] = s;
            }
        }
        #pragma unroll
        for (int j = 0; j < 4; j++) {
            float c = colacc[j];
            c += __shfl_xor(c, 16);
            c += __shfl_xor(c, 32);
            if (lane < 16) pcol[colBase + waveCol + 16 * j + lc] = c;
        }
    }
}

// ---------------- K3: coalesced transpose-reduce partial -> rowsum ----------
__global__ void __launch_bounds__(256) reduce_kernel(
        const float* __restrict__ partial, float* __restrict__ rowsum) {
    const int tid  = threadIdx.x;
    const int wave = tid >> 6;
    const int lane = tid & 63;
    const int r0 = blockIdx.x * 64;
    float s = 0.0f;
    #pragma unroll
    for (int k = 0; k < 32; ++k) {
        const int slot = wave + k * 4;
        s += partial[(size_t)slot * ROWS + r0 + lane];
    }
    __shared__ float red[4][64];
    red[wave][lane] = s;
    __syncthreads();
    if (wave == 0)
        rowsum[r0 + lane] = red[0][lane] + red[1][lane]
                          + red[2][lane] + red[3][lane];
}

// ---------------- K4: per-pair loss -> blockpart (no atomics) ----------------
__global__ void __launch_bounds__(256) loss_kernel(
        const float* __restrict__ z1, const float* __restrict__ z2,
        const float* __restrict__ invnorm, const float* __restrict__ rowsum,
        float* __restrict__ blockpart) {
    const int tid  = threadIdx.x;
    const int wave = tid >> 6;
    const int lane = tid & 63;
    const int p = blockIdx.x * 4 + wave;     // pair 0..4095; rows p, p+NPAIR
    float4 a = ((const float4*)(z1 + (size_t)p * DIM))[lane];
    float4 b = ((const float4*)(z2 + (size_t)p * DIM))[lane];
    float d = sum64(a.x * b.x + a.y * b.y + a.z * b.z + a.w * b.w);
    __shared__ float wp[4];
    if (lane == 0) {
        float sim = d * invnorm[p] * invnorm[p + NPAIR] * 10.0f;
        wp[wave] = logf(rowsum[p]) + logf(rowsum[p + NPAIR]) - 2.0f * sim;
    }
    __syncthreads();
    if (tid == 0)
        blockpart[blockIdx.x] = wp[0] + wp[1] + wp[2] + wp[3];
}

// ---------------- K5: final reduce (single block) ----------------
__global__ void __launch_bounds__(256) final_kernel(
        const float* __restrict__ blockpart, float* __restrict__ out) {
    const int tid = threadIdx.x;
    float s = blockpart[tid] + blockpart[tid + 256]
            + blockpart[tid + 512] + blockpart[tid + 768];
    s = sum64(s);
    __shared__ float wpart[4];
    if ((tid & 63) == 0) wpart[tid >> 6] = s;
    __syncthreads();
    if (tid == 0)
        out[0] = (wpart[0] + wpart[1] + wpart[2] + wpart[3]) * (1.0f / ROWS);
}

extern "C" void kernel_launch(void* const* d_in, const int* in_sizes, int n_in,
                              void* d_out, int out_size, void* d_ws, size_t ws_size,
                              hipStream_t stream) {
    const float* z1 = (const float*)d_in[0];
    const float* z2 = (const float*)d_in[1];
    float* out = (float*)d_out;

    char* ws = (char*)d_ws;
    unsigned char* zT16 = (unsigned char*)ws;                       // 2 MiB
    float* partial   = (float*)(ws + (size_t)2 * 1024 * 1024);      // 4 MiB [slot][row]
    float* invnorm   = (float*)(ws + (size_t)6 * 1024 * 1024);      // 32 KiB
    float* rowsum    = (float*)(ws + (size_t)6 * 1024 * 1024 + 32768);   // 32 KiB
    float* blockpart = (float*)(ws + (size_t)6 * 1024 * 1024 + 65536);   // 4 KiB

    prep_kernel<<<ROWS / 16, 256, 0, stream>>>(z1, z2, zT16, invnorm);
    simsum_kernel<<<NTILE, 256, 0, stream>>>(zT16, partial);
    reduce_kernel<<<ROWS / 64, 256, 0, stream>>>(partial, rowsum);
    loss_kernel<<<NPAIR / 4, 256, 0, stream>>>(z1, z2, invnorm, rowsum, blockpart);
    final_kernel<<<1, 256, 0, stream>>>(blockpart, out);
}